// Round 1
// baseline (109.800 us; speedup 1.0000x reference)
//
#include <hip/hip_runtime.h>

#define B_   4
#define Hf   128
#define Wf   128
#define C_   128
#define HC   32
#define WC   32
#define SR   15
#define PAD  7
#define FR   125
#define FRP  139

// ---- kernel 1: f_c = avg_pool(features_0, 4, stride 4) -> (4,32,32,128) ----
__global__ __launch_bounds__(256) void pool_fc(const float* __restrict__ in0,
                                               float* __restrict__ fc) {
    int t = blockIdx.x * 256 + threadIdx.x;          // B*32*32*32 float4 = 131072
    int c4 = t & 31;
    int j  = (t >> 5) & 31;
    int i  = (t >> 10) & 31;
    int b  = t >> 15;
    const float4* in = reinterpret_cast<const float4*>(in0);
    int base = ((b * Hf + 4 * i) * Wf + 4 * j) * 32 + c4;   // float4 units
    float4 acc = make_float4(0.f, 0.f, 0.f, 0.f);
#pragma unroll
    for (int dy = 0; dy < 4; ++dy)
#pragma unroll
        for (int dx = 0; dx < 4; ++dx) {
            float4 v = in[base + dy * (Wf * 32) + dx * 32];
            acc.x += v.x; acc.y += v.y; acc.z += v.z; acc.w += v.w;
        }
    const float s = 1.0f / 16.0f;
    acc.x *= s; acc.y *= s; acc.z *= s; acc.w *= s;
    reinterpret_cast<float4*>(fc)[t] = acc;
}

// ---- kernel 2: f_r_pad = pad(avg_pool(features_0from1,4,stride 1), 7) -> (4,139,139,128) ----
__global__ __launch_bounds__(256) void pool_fr(const float* __restrict__ in1,
                                               float* __restrict__ frp) {
    int t = blockIdx.x * 256 + threadIdx.x;
    const int total = B_ * FRP * FRP * 32;           // float4 count
    if (t >= total) return;
    int c4 = t & 31;
    int r  = t >> 5;
    int x  = r % FRP; r /= FRP;
    int y  = r % FRP;
    int b  = r / FRP;
    float4 acc = make_float4(0.f, 0.f, 0.f, 0.f);
    int yy = y - PAD, xx = x - PAD;
    if (yy >= 0 && yy < FR && xx >= 0 && xx < FR) {
        const float4* in = reinterpret_cast<const float4*>(in1);
        int base = ((b * Hf + yy) * Wf + xx) * 32 + c4;
#pragma unroll
        for (int dy = 0; dy < 4; ++dy)
#pragma unroll
            for (int dx = 0; dx < 4; ++dx) {
                float4 v = in[base + dy * (Wf * 32) + dx * 32];
                acc.x += v.x; acc.y += v.y; acc.z += v.z; acc.w += v.w;
            }
        const float s = 1.0f / 16.0f;
        acc.x *= s; acc.y *= s; acc.z *= s; acc.w *= s;
    }
    reinterpret_cast<float4*>(frp)[t] = acc;
}

// ---- kernel 3: correlation + leaky_relu + 4x4 replicate ----
// one block per (b,i,j); thread t<225 owns displacement (u,v)
__global__ __launch_bounds__(256) void corr_kernel(const float* __restrict__ fc,
                                                   const float* __restrict__ frp,
                                                   float* __restrict__ out) {
    int blk = blockIdx.x;
    int j = blk & 31;
    int i = (blk >> 5) & 31;
    int b = blk >> 10;

    __shared__ float4 fcs[32];
    int tid = threadIdx.x;
    if (tid < 32)
        fcs[tid] = reinterpret_cast<const float4*>(fc)[((b * HC + i) * WC + j) * 32 + tid];
    __syncthreads();

    if (tid >= SR * SR) return;

    int u = tid / SR, v = tid - u * SR;
    int row = 4 * i + u, col = 4 * j + v;
    const float4* p = reinterpret_cast<const float4*>(frp) + ((b * FRP + row) * FRP + col) * 32;

    float acc = 0.f;
#pragma unroll
    for (int k = 0; k < 32; ++k) {
        float4 a = fcs[k];
        float4 r = p[k];
        acc = fmaf(a.x, r.x, acc);
        acc = fmaf(a.y, r.y, acc);
        acc = fmaf(a.z, r.z, acc);
        acc = fmaf(a.w, r.w, acc);
    }
    acc *= (1.0f / 128.0f);
    float val = acc > 0.f ? acc : 0.1f * acc;

    // replicate to the 4x4 pixel block; s-dim (225) is innermost -> coalesced
    long base = (long)((b * Hf + 4 * i) * Wf + 4 * j) * (SR * SR) + tid;
#pragma unroll
    for (int di = 0; di < 4; ++di)
#pragma unroll
        for (int dj = 0; dj < 4; ++dj)
            out[base + (long)(di * Wf + dj) * (SR * SR)] = val;
}

extern "C" void kernel_launch(void* const* d_in, const int* in_sizes, int n_in,
                              void* d_out, int out_size, void* d_ws, size_t ws_size,
                              hipStream_t stream) {
    const float* f0 = (const float*)d_in[0];
    const float* f1 = (const float*)d_in[1];
    float* out = (float*)d_out;

    float* fc  = (float*)d_ws;                       // 4*32*32*128 = 524288 floats (2 MB)
    float* frp = fc + B_ * HC * WC * C_;             // 4*139*139*128 floats (39.6 MB)

    pool_fc<<<(B_ * HC * WC * 32) / 256, 256, 0, stream>>>(f0, fc);

    int frp_threads = B_ * FRP * FRP * 32;
    pool_fr<<<(frp_threads + 255) / 256, 256, 0, stream>>>(f1, frp);

    corr_kernel<<<B_ * HC * WC, 256, 0, stream>>>(fc, frp, out);
}

// Round 2
// 63.435 us; speedup vs baseline: 1.7309x; 1.7309x over previous
//
#include <hip/hip_runtime.h>

#define B_   4
#define Hf   128
#define Wf   128
#define C_   128
#define HC   32
#define WC   32
#define SR   15
#define PAD  7
#define FR   125      // 125x125 pooled (unpadded) grid

// ---- kernel 1: f_c = avg_pool(features_0, 4, stride 4) -> (4,32,32,128) ----
__global__ __launch_bounds__(256) void pool_fc(const float* __restrict__ in0,
                                               float* __restrict__ fc) {
    int t = blockIdx.x * 256 + threadIdx.x;          // B*32*32*32 float4 = 131072
    int c4 = t & 31;
    int j  = (t >> 5) & 31;
    int i  = (t >> 10) & 31;
    int b  = t >> 15;
    const float4* in = reinterpret_cast<const float4*>(in0);
    int base = ((b * Hf + 4 * i) * Wf + 4 * j) * 32 + c4;   // float4 units
    float4 acc = make_float4(0.f, 0.f, 0.f, 0.f);
#pragma unroll
    for (int dy = 0; dy < 4; ++dy)
#pragma unroll
        for (int dx = 0; dx < 4; ++dx) {
            float4 v = in[base + dy * (Wf * 32) + dx * 32];
            acc.x += v.x; acc.y += v.y; acc.z += v.z; acc.w += v.w;
        }
    const float s = 1.0f / 16.0f;
    acc.x *= s; acc.y *= s; acc.z *= s; acc.w *= s;
    reinterpret_cast<float4*>(fc)[t] = acc;
}

// ---- kernel 2: f_r = avg_pool(features_0from1, 4, stride 1) -> (4,125,125,128), NO pad ----
// vertical strip: each thread produces 8 output rows from 11 horizontal row-sums
__device__ inline float4 hsum4(const float4* __restrict__ base, int row, int xcol) {
    float4 s = make_float4(0.f, 0.f, 0.f, 0.f);
#pragma unroll
    for (int dx = 0; dx < 4; ++dx) {
        float4 v = base[(row * Wf + xcol + dx) * 32];
        s.x += v.x; s.y += v.y; s.z += v.z; s.w += v.w;
    }
    return s;
}

__global__ __launch_bounds__(256) void pool_fr(const float* __restrict__ in1,
                                               float* __restrict__ fr) {
    // grid: b(4) * xtile(16) * strip(16); block 256: c4 = tid&31, xo = tid>>5
    int blk   = blockIdx.x;
    int strip = blk & 15;
    int xt    = (blk >> 4) & 15;
    int b     = blk >> 8;
    int c4    = threadIdx.x & 31;
    int x     = xt * 8 + (threadIdx.x >> 5);
    if (x >= FR) return;
    int y0 = strip * 8;

    const float4* base = reinterpret_cast<const float4*>(in1) + (b * Hf * Wf) * 32 + c4;
    float4* fr4 = reinterpret_cast<float4*>(fr);

    float4 h[11];
#pragma unroll
    for (int k = 0; k < 11; ++k) {
        int r = y0 + k; if (r > Hf - 1) r = Hf - 1;   // clamp; clamped rows only feed masked outputs
        h[k] = hsum4(base, r, x);
    }
    const float s = 1.0f / 16.0f;
#pragma unroll
    for (int yy = 0; yy < 8; ++yy) {
        int y = y0 + yy;
        if (y < FR) {
            float4 o;
            o.x = (h[yy].x + h[yy+1].x + h[yy+2].x + h[yy+3].x) * s;
            o.y = (h[yy].y + h[yy+1].y + h[yy+2].y + h[yy+3].y) * s;
            o.z = (h[yy].z + h[yy+1].z + h[yy+2].z + h[yy+3].z) * s;
            o.w = (h[yy].w + h[yy+1].w + h[yy+2].w + h[yy+3].w) * s;
            fr4[((b * FR + y) * FR + x) * 32 + c4] = o;
        }
    }
}

// ---- kernel 3: correlation + leaky_relu + 4x4 replicate ----
// block per coarse cell (XCD-swizzled); 8 groups x 32 lanes; lane = channel chunk
__global__ __launch_bounds__(256) void corr_kernel(const float* __restrict__ fc,
                                                   const float* __restrict__ fr,
                                                   float* __restrict__ out) {
    int blk  = blockIdx.x;
    int cell = (blk & 7) * 512 + (blk >> 3);         // XCD-aware swizzle (4096 % 8 == 0)
    int j = cell & 31;
    int i = (cell >> 5) & 31;
    int b = cell >> 10;

    int tid  = threadIdx.x;
    int lane = tid & 31;
    int grp  = tid >> 5;                             // 0..7

    __shared__ float corr_s[232];

    const float4* fr4 = reinterpret_cast<const float4*>(fr);
    float4 f = reinterpret_cast<const float4*>(fc)[((b * HC + i) * WC + j) * 32 + lane];

    for (int it = 0; it < 29; ++it) {
        int uv = it * 8 + grp;
        float acc = 0.f;
        int u = uv / SR, v = uv - u * SR;
        int row = 4 * i + u - PAD;
        int col = 4 * j + v - PAD;
        if (uv < SR * SR && row >= 0 && row < FR && col >= 0 && col < FR) {
            float4 r = fr4[((b * FR + row) * FR + col) * 32 + lane];
            acc = fmaf(f.x, r.x, fmaf(f.y, r.y, fmaf(f.z, r.z, f.w * r.w)));
        }
        // butterfly reduce within each 32-lane group
        acc += __shfl_xor(acc, 16);
        acc += __shfl_xor(acc, 8);
        acc += __shfl_xor(acc, 4);
        acc += __shfl_xor(acc, 2);
        acc += __shfl_xor(acc, 1);
        if (uv < SR * SR && lane == 0) {
            float c = acc * (1.0f / 128.0f);
            corr_s[uv] = c > 0.f ? c : 0.1f * c;
        }
    }
    __syncthreads();

    // write 16 pixels x 225 values, coalesced (900 consecutive floats per di)
    long base = (long)((b * Hf + 4 * i) * Wf + 4 * j) * (SR * SR);
#pragma unroll
    for (int di = 0; di < 4; ++di) {
        long rb = base + (long)di * Wf * (SR * SR);
        for (int q = tid; q < 4 * SR * SR; q += 256)
            out[rb + q] = corr_s[q % (SR * SR)];
    }
}

extern "C" void kernel_launch(void* const* d_in, const int* in_sizes, int n_in,
                              void* d_out, int out_size, void* d_ws, size_t ws_size,
                              hipStream_t stream) {
    const float* f0 = (const float*)d_in[0];
    const float* f1 = (const float*)d_in[1];
    float* out = (float*)d_out;

    float* fc = (float*)d_ws;                        // 4*32*32*128 floats (2 MB)
    float* fr = fc + B_ * HC * WC * C_;              // 4*125*125*128 floats (32 MB)

    pool_fc<<<(B_ * HC * WC * 32) / 256, 256, 0, stream>>>(f0, fc);
    pool_fr<<<B_ * 16 * 16, 256, 0, stream>>>(f1, fr);
    corr_kernel<<<B_ * HC * WC, 256, 0, stream>>>(fc, fr, out);
}